// Round 11
// baseline (13728.812 us; speedup 1.0000x reference)
//
#include <hip/hip_runtime.h>
#include <math.h>

#define N_NODES 100000
#define N_EDGES 3200000
#define BS 256

// ==================== setup: deterministic CSR construction ====================
// All-f32 data path, rounding-matched to the numpy reference (absmax 8.4e-11,
// rounds 7/8/9):
//  - bucket sums in ascending edge-id order (np.add.at semantics)
//  - products rounded separately from adds in the SpMV (np: norm*h then add.at)
//  - matmuls as ascending-k fmaf chains from 0, then one add
//  - dis = 1/sqrtf
// f64 is provably WRONG here (4 distinct f64 impls -> absmax 0.9999987).
// EVERY fp chain must stay bit-identical under refactors: parallelize only
// across independent chains (channels, rows), never within one.
//
// Perf model (r9 counters): prop kernels are bound by gather LINE traffic
// (FETCH 207MB/dispatch on L3 layer, VALUBusy 1.6%). Fix: line-align h rows
// (stride 32 floats = 128B for the 20-ch layer) -> 1 line/edge instead of
// 1.625; unroll-by-2 for MLP; nontemporal edge-stream loads (as i64 — the
// builtin rejects HIP vector types like int2).

__global__ void count_kernel(const int* __restrict__ key, int* __restrict__ cnt) {
    int e = blockIdx.x * blockDim.x + threadIdx.x;
    if (e < N_EDGES) atomicAdd(&cnt[key[e]], 1);
}

__global__ void scan_partial_kernel(const int* __restrict__ cnt, int* __restrict__ bsums) {
    __shared__ int lds[256];
    int tid = threadIdx.x;
    int base = blockIdx.x * 1024 + tid * 4;
    int s = 0;
#pragma unroll
    for (int i = 0; i < 4; ++i) s += (base + i < N_NODES) ? cnt[base + i] : 0;
    lds[tid] = s;
    __syncthreads();
    for (int off = 128; off > 0; off >>= 1) {
        if (tid < off) lds[tid] += lds[tid + off];
        __syncthreads();
    }
    if (tid == 0) bsums[blockIdx.x] = lds[0];
}

__global__ void scan_bsums_kernel(int* __restrict__ bsums, int nb, int* __restrict__ total_out) {
    if (threadIdx.x == 0 && blockIdx.x == 0) {
        int acc = 0;
        for (int b = 0; b < nb; ++b) {
            int v = bsums[b];
            bsums[b] = acc;
            acc += v;
        }
        *total_out = acc;
    }
}

__global__ void scan_final_kernel(const int* __restrict__ cnt, const int* __restrict__ bsums,
                                  int* __restrict__ rp) {
    __shared__ int lds[256];
    int tid = threadIdx.x;
    int base = blockIdx.x * 1024 + tid * 4;
    int v[4];
    int ts = 0;
#pragma unroll
    for (int i = 0; i < 4; ++i) {
        v[i] = (base + i < N_NODES) ? cnt[base + i] : 0;
        ts += v[i];
    }
    lds[tid] = ts;
    __syncthreads();
    for (int off = 1; off < 256; off <<= 1) {
        int t = (tid >= off) ? lds[tid - off] : 0;
        __syncthreads();
        lds[tid] += t;
        __syncthreads();
    }
    int run = lds[tid] - ts + bsums[blockIdx.x];
#pragma unroll
    for (int i = 0; i < 4; ++i) {
        if (base + i < N_NODES) rp[base + i] = run;
        run += v[i];
    }
}

__global__ void bucket_fill_kernel(const int* __restrict__ key, int* __restrict__ fill,
                                   int* __restrict__ raw) {
    int e = blockIdx.x * blockDim.x + threadIdx.x;
    if (e >= N_EDGES) return;
    int slot = atomicAdd(&fill[key[e]], 1);
    raw[slot] = e;
}

// per-row rank-selection sort by edge id: deterministic final layout
__global__ void sort_rows_kernel(const int* __restrict__ rp, const int* __restrict__ raw,
                                 int* __restrict__ sorted) {
    int n = blockIdx.x * blockDim.x + threadIdx.x;
    if (n >= N_NODES) return;
    int beg = rp[n], end = rp[n + 1];
    for (int i = beg; i < end; ++i) {
        int v = raw[i];
        int r = 0;
        for (int j = beg; j < end; ++j) r += (raw[j] < v);
        sorted[beg + r] = v;
    }
}

// dis[n] = 1/sqrtf(f32 sum of w over src-row n, ascending edge id), 0 if deg<=0
__global__ void deg_dis_kernel(const int* __restrict__ rp_src, const int* __restrict__ sorted,
                               const float* __restrict__ w, float* __restrict__ dis) {
#pragma clang fp contract(off)
    {
        int n = blockIdx.x * blockDim.x + threadIdx.x;
        if (n >= N_NODES) return;
        float d = 0.f;
        int beg = rp_src[n], end = rp_src[n + 1];
        for (int j = beg; j < end; ++j) d = d + w[sorted[j]];
        dis[n] = (d > 0.f) ? (1.0f / sqrtf(d)) : 0.f;
    }
}

// packed[j] = (u64) { lo32 = src, hi32 = bits(((-dis[s]) * w) * dis[d]) }
__global__ void csr_fill_kernel(const int* __restrict__ sorted, const int* __restrict__ src,
                                const int* __restrict__ dst, const float* __restrict__ w,
                                const float* __restrict__ dis,
                                unsigned long long* __restrict__ packed) {
#pragma clang fp contract(off)
    {
        int j = blockIdx.x * blockDim.x + threadIdx.x;
        if (j >= N_EDGES) return;
        int e = sorted[j];
        int s = src[e], d = dst[e];
        float cw = ((-dis[s]) * w[e]) * dis[d];
        packed[j] = ((unsigned long long)(unsigned int)__float_as_int(cw) << 32) |
                    (unsigned long long)(unsigned int)s;
    }
}

// ==================== per-layer kernels (f32, rounding-matched) ====================

// thread per (n,co): acc[n*SACC+co] = fmaf-chain over ci of hin[n*SIN+ci]*W0[ci,co]
template <int CIN, int COUT, int SIN, int SACC>
__global__ void layer_init_kernel(const float* __restrict__ hin, const float* __restrict__ W0,
                                  float* __restrict__ acc) {
    int t = blockIdx.x * blockDim.x + threadIdx.x;
    if (t >= N_NODES * COUT) return;
    int n = t / COUT, co = t - n * COUT;
    const float* hr = hin + (size_t)n * SIN;
    float m = 0.f;
#pragma unroll
    for (int ci = 0; ci < CIN; ++ci) m = fmaf(hr[ci], W0[ci * COUT + co], m);
    acc[(size_t)n * SACC + co] = m;
}

__device__ __forceinline__ void unpack_edge(unsigned long long p, int& s, float& w) {
    s = (int)(unsigned int)(p & 0xffffffffull);
    w = __int_as_float((int)(unsigned int)(p >> 32));
}

// Grouped-channel prop+matmul. Block = R rows x LANES lanes; lane owns GS
// consecutive channels (GS=4 -> one aligned float4 gather per edge).
// Per-channel gather chains in ascending edge-id order (mul rounded then add);
// recurrence; LDS handoff; ascending-ci fmaf matmul chain; acc += m.
// All chains bit-identical to r7. Edge loop manually unrolled x2: both loads
// issue before the (order-preserved) add chains -> 2x MLP.
template <int CIN, int COUT, int SIN, int SACC, int GS, int LANES, int R>
__global__ __launch_bounds__(LANES* R) void prop_mm_kernel(
    const int* __restrict__ rp, const unsigned long long* __restrict__ pk,
    const float* __restrict__ hin, const float* __restrict__ prev,
    const float* __restrict__ Wk, int rec, float* __restrict__ tx_out,
    float* __restrict__ acc) {
#pragma clang fp contract(off)
    {
        __shared__ float tls[R][LANES * GS];
        int r = threadIdx.x / LANES;
        int lane = threadIdx.x - r * LANES;
        int n = blockIdx.x * R + r;
        bool vn = (n < N_NODES);
        if (vn) {
            int c0 = lane * GS;
            float s[GS];
#pragma unroll
            for (int g = 0; g < GS; ++g) s[g] = 0.f;
            int beg = rp[n], end = rp[n + 1];
            int j = beg;
            if constexpr (GS == 4) {
                for (; j + 1 < end; j += 2) {
                    unsigned long long pa = __builtin_nontemporal_load(&pk[j]);
                    unsigned long long pb = __builtin_nontemporal_load(&pk[j + 1]);
                    int sa, sb;
                    float wa, wb;
                    unpack_edge(pa, sa, wa);
                    unpack_edge(pb, sb, wb);
                    const float4 qa = *reinterpret_cast<const float4*>(hin + (size_t)sa * SIN + c0);
                    const float4 qb = *reinterpret_cast<const float4*>(hin + (size_t)sb * SIN + c0);
                    s[0] = s[0] + (wa * qa.x);
                    s[1] = s[1] + (wa * qa.y);
                    s[2] = s[2] + (wa * qa.z);
                    s[3] = s[3] + (wa * qa.w);
                    s[0] = s[0] + (wb * qb.x);
                    s[1] = s[1] + (wb * qb.y);
                    s[2] = s[2] + (wb * qb.z);
                    s[3] = s[3] + (wb * qb.w);
                }
                if (j < end) {
                    unsigned long long p = __builtin_nontemporal_load(&pk[j]);
                    int sp;
                    float w;
                    unpack_edge(p, sp, w);
                    const float4 q = *reinterpret_cast<const float4*>(hin + (size_t)sp * SIN + c0);
                    s[0] = s[0] + (w * q.x);
                    s[1] = s[1] + (w * q.y);
                    s[2] = s[2] + (w * q.z);
                    s[3] = s[3] + (w * q.w);
                }
            } else {
                for (; j + 1 < end; j += 2) {
                    unsigned long long pa = __builtin_nontemporal_load(&pk[j]);
                    unsigned long long pb = __builtin_nontemporal_load(&pk[j + 1]);
                    int sa, sb;
                    float wa, wb;
                    unpack_edge(pa, sa, wa);
                    unpack_edge(pb, sb, wb);
                    float qa = hin[(size_t)sa * SIN + c0];
                    float qb = hin[(size_t)sb * SIN + c0];
                    s[0] = s[0] + (wa * qa);
                    s[0] = s[0] + (wb * qb);
                }
                if (j < end) {
                    unsigned long long p = __builtin_nontemporal_load(&pk[j]);
                    int sp;
                    float w;
                    unpack_edge(p, sp, w);
                    s[0] = s[0] + (w * hin[(size_t)sp * SIN + c0]);
                }
            }
            float t[GS];
            if (rec) {
#pragma unroll
                for (int g = 0; g < GS; ++g) t[g] = 2.f * s[g] - prev[(size_t)n * SIN + c0 + g];
            } else {
#pragma unroll
                for (int g = 0; g < GS; ++g) t[g] = s[g];
            }
#pragma unroll
            for (int g = 0; g < GS; ++g) tls[r][c0 + g] = t[g];
            if constexpr (GS == 4) {
                *reinterpret_cast<float4*>(tx_out + (size_t)n * SIN + c0) =
                    make_float4(t[0], t[1], t[2], t[3]);
            } else {
                tx_out[(size_t)n * SIN + c0] = t[0];
            }
        }
        __syncthreads();
        if (vn) {
            for (int co = lane; co < COUT; co += LANES) {
                float m = 0.f;
#pragma unroll
                for (int ci = 0; ci < CIN; ++ci) m = fmaf(tls[r][ci], Wk[ci * COUT + co], m);
                acc[(size_t)n * SACC + co] = acc[(size_t)n * SACC + co] + m;
            }
        }
    }
}

// a = silu(a + b) at padded stride S, real channels C only
template <int C, int S>
__global__ void silu_bias_kernel(float* __restrict__ a, const float* __restrict__ b) {
#pragma clang fp contract(off)
    {
        int t = blockIdx.x * blockDim.x + threadIdx.x;
        if (t >= N_NODES * C) return;
        int n = t / C, c = t - n * C;
        float x = a[(size_t)n * S + c] + b[c];
        float sig = 1.f / (1.f + expf(-x));
        a[(size_t)n * S + c] = x * sig;
    }
}

// out[n] = sigmoid(h[n,:27] @ W4), h at stride 32
__global__ void final_kernel(const float* __restrict__ h, const float* __restrict__ W4,
                             float* __restrict__ out) {
#pragma clang fp contract(off)
    {
        int n = blockIdx.x * blockDim.x + threadIdx.x;
        if (n >= N_NODES) return;
        const float* hr = h + (size_t)n * 32;
        float m = 0.f;
#pragma unroll
        for (int ci = 0; ci < 27; ++ci) m = fmaf(hr[ci], W4[ci], m);
        out[n] = 1.f / (1.f + expf(-m));
    }
}

__global__ void signal_kernel(float* __restrict__ out, float val) {
    int n = blockIdx.x * blockDim.x + threadIdx.x;
    if (n < N_NODES) out[n] = val;
}

// ==================== host driver ====================

static void run_scan(const int* cnt, int* bsums, int* rp, hipStream_t stream) {
    const int nb = (N_NODES + 1023) / 1024;  // 98
    scan_partial_kernel<<<nb, 256, 0, stream>>>(cnt, bsums);
    scan_bsums_kernel<<<1, 64, 0, stream>>>(bsums, nb, rp + N_NODES);
    scan_final_kernel<<<nb, 256, 0, stream>>>(cnt, bsums, rp);
}

template <int CIN, int COUT, int SIN, int SACC, int GS, int LANES, int R>
static void run_layer(int K, const float* hin, const float* W, float* acc, float* b0, float* b1,
                      float* b2, const int* rp, const unsigned long long* pk,
                      hipStream_t stream) {
    const int gInit = (N_NODES * COUT + BS - 1) / BS;
    const int gProp = (N_NODES + R - 1) / R;
    layer_init_kernel<CIN, COUT, SIN, SACC><<<gInit, BS, 0, stream>>>(hin, W, acc);
    if (K > 1) {
        float* bufs[3] = {b0, b1, b2};
        prop_mm_kernel<CIN, COUT, SIN, SACC, GS, LANES, R><<<gProp, LANES * R, 0, stream>>>(
            rp, pk, hin, nullptr, W + 1 * CIN * COUT, 0, bufs[0], acc);
        const float* pm2 = hin;      // tx_{k-2}
        const float* pm1 = bufs[0];  // tx_{k-1}
        for (int k = 2; k < K; ++k) {
            float* outb = bufs[(k - 1) % 3];  // k=2->b1, k=3->b2, k=4->b0, ...
            prop_mm_kernel<CIN, COUT, SIN, SACC, GS, LANES, R><<<gProp, LANES * R, 0, stream>>>(
                rp, pk, pm1, pm2, W + k * CIN * COUT, 1, outb, acc);
            pm2 = pm1;
            pm1 = outb;
        }
    }
}

extern "C" void kernel_launch(void* const* d_in, const int* in_sizes, int n_in, void* d_out,
                              int out_size, void* d_ws, size_t ws_size, hipStream_t stream) {
    const float* x  = (const float*)d_in[0];
    const int* idx  = (const int*)d_in[1];
    const float* ew = (const float*)d_in[2];
    const float* W1 = (const float*)d_in[3];
    const float* b1 = (const float*)d_in[4];
    const float* W2 = (const float*)d_in[5];
    const float* b2 = (const float*)d_in[6];
    const float* W3 = (const float*)d_in[7];
    const float* b3 = (const float*)d_in[8];
    const float* W4 = (const float*)d_in[9];
    float* out = (float*)d_out;
    (void)in_sizes; (void)n_in; (void)out_size;

    const int* src = idx;
    const int* dst = idx + N_EDGES;

    // workspace carve-up (256B aligned) — ~97.3 MB (< proven-available 126 MB, r6)
    size_t off = 0;
    auto alloc = [&](size_t bytes) {
        size_t o = off;
        off = (off + bytes + 255) & ~(size_t)255;
        return o;
    };
    char* ws = (char*)d_ws;
    int*   cnt     = (int*)(ws + alloc(N_NODES * 4));          // counts -> fill cursors
    int*   rp_src  = (int*)(ws + alloc((N_NODES + 1) * 4));
    int*   rp_dst  = (int*)(ws + alloc((N_NODES + 1) * 4));
    float* dis     = (float*)(ws + alloc(N_NODES * 4));
    int*   bsums   = (int*)(ws + alloc(512));
    unsigned long long* packed = (unsigned long long*)(ws + alloc((size_t)N_EDGES * 8));
    float* t0      = (float*)(ws + alloc((size_t)N_NODES * 32 * 4));  // tx ping-pong, stride<=32
    float* t1      = (float*)(ws + alloc((size_t)N_NODES * 32 * 4));
    float* t2      = (float*)(ws + alloc((size_t)N_NODES * 32 * 4));
    float* accA    = (float*)(ws + alloc((size_t)N_NODES * 16 * 4));  // L1 out, stride 16 (64B)
    float* accB    = (float*)(ws + alloc((size_t)N_NODES * 32 * 4));  // L2 out, stride 32 (128B)
    float* accC    = (float*)(ws + alloc((size_t)N_NODES * 32 * 4));  // L3 out, stride 32
    const size_t NEED = off;
    // setup-only aliases (t bufs dead during setup; each 12.8MB fits one t buf):
    int* raw    = (int*)t0;
    int* sorted = (int*)t1;

    int gE = (N_EDGES + BS - 1) / BS;
    int gN = (N_NODES + BS - 1) / BS;

    if (ws_size < NEED) {  // diagnostic: reveal ws_size as 6000+MB in absmax
        signal_kernel<<<gN, BS, 0, stream>>>(
            out, 6000.0f + (float)(ws_size / (1024.0 * 1024.0)));
        return;
    }

    // ---- src-keyed buckets -> deterministic deg -> dis ----
    (void)hipMemsetAsync(cnt, 0, N_NODES * 4, stream);
    count_kernel<<<gE, BS, 0, stream>>>(src, cnt);
    run_scan(cnt, bsums, rp_src, stream);
    (void)hipMemcpyAsync(cnt, rp_src, N_NODES * 4, hipMemcpyDeviceToDevice, stream);
    bucket_fill_kernel<<<gE, BS, 0, stream>>>(src, cnt, raw);
    sort_rows_kernel<<<gN, BS, 0, stream>>>(rp_src, raw, sorted);
    deg_dis_kernel<<<gN, BS, 0, stream>>>(rp_src, sorted, ew, dis);

    // ---- dst-keyed buckets -> deterministic packed CSR ----
    (void)hipMemsetAsync(cnt, 0, N_NODES * 4, stream);
    count_kernel<<<gE, BS, 0, stream>>>(dst, cnt);
    run_scan(cnt, bsums, rp_dst, stream);
    (void)hipMemcpyAsync(cnt, rp_dst, N_NODES * 4, hipMemcpyDeviceToDevice, stream);
    bucket_fill_kernel<<<gE, BS, 0, stream>>>(dst, cnt, raw);
    sort_rows_kernel<<<gN, BS, 0, stream>>>(rp_dst, raw, sorted);
    csr_fill_kernel<<<gE, BS, 0, stream>>>(sorted, src, dst, ew, dis, packed);

    // ---- layers ----
    // L1: CIN=2 (x, stride 2), out accA stride 16; 2 lanes x 128 rows (256 thr)
    run_layer<2, 14, 2, 16, 1, 2, 128>(39, x, W1, accA, t0, t1, t2, rp_dst, packed, stream);
    silu_bias_kernel<14, 16><<<(N_NODES * 14 + BS - 1) / BS, BS, 0, stream>>>(accA, b1);
    // L2: CIN=14 @ stride 16 (64B rows, sector-aligned), out accB stride 32; 4x64 (256 thr)
    run_layer<14, 20, 16, 32, 4, 4, 64>(43, accA, W2, accB, t0, t1, t2, rp_dst, packed, stream);
    silu_bias_kernel<20, 32><<<(N_NODES * 20 + BS - 1) / BS, BS, 0, stream>>>(accB, b2);
    // L3: CIN=20 @ stride 32 (128B rows, LINE-aligned -> 1 line/edge), out accC stride 32; 5x64 (320 thr)
    run_layer<20, 27, 32, 32, 4, 5, 64>(45, accB, W3, accC, t0, t1, t2, rp_dst, packed, stream);
    silu_bias_kernel<27, 32><<<(N_NODES * 27 + BS - 1) / BS, BS, 0, stream>>>(accC, b3);
    final_kernel<<<gN, BS, 0, stream>>>(accC, W4, out);
}

// Round 12
// 9539.620 us; speedup vs baseline: 1.4391x; 1.4391x over previous
//
#include <hip/hip_runtime.h>
#include <math.h>

#define N_NODES 100000
#define N_EDGES 3200000
#define BS 256

// ==================== setup: deterministic CSR construction ====================
// All-f32 data path, rounding-matched to the numpy reference (absmax 8.4e-11,
// rounds 7/8/9/11):
//  - bucket sums in ascending edge-id order (np.add.at semantics)
//  - products rounded separately from adds in the SpMV (np: norm*h then add.at)
//  - matmuls as ascending-k fmaf chains from 0, then one add
//  - dis = 1/sqrtf
// f64 is provably WRONG here (4 distinct f64 impls -> absmax 0.9999987).
// EVERY fp chain must stay bit-identical under refactors: parallelize only
// across independent chains (channels, rows), never within one.
//
// Perf model (r9 vs r11 A/B): prop gathers are bound by local-XCD L2 hit rate
// + cross-XCD fabric traffic -> gathered state must stay PACKED (8 MB @ stride
// 20 beats 12.8 MB @ stride 32 by 35% wall time). No nontemporal on pk (it is
// re-read by all 124 dispatches; L2/L3 residency matters). This round = r9
// layout + unroll-2 plain loads (2x MLP) + L1 single-lane float2 gather.

__global__ void count_kernel(const int* __restrict__ key, int* __restrict__ cnt) {
    int e = blockIdx.x * blockDim.x + threadIdx.x;
    if (e < N_EDGES) atomicAdd(&cnt[key[e]], 1);
}

__global__ void scan_partial_kernel(const int* __restrict__ cnt, int* __restrict__ bsums) {
    __shared__ int lds[256];
    int tid = threadIdx.x;
    int base = blockIdx.x * 1024 + tid * 4;
    int s = 0;
#pragma unroll
    for (int i = 0; i < 4; ++i) s += (base + i < N_NODES) ? cnt[base + i] : 0;
    lds[tid] = s;
    __syncthreads();
    for (int off = 128; off > 0; off >>= 1) {
        if (tid < off) lds[tid] += lds[tid + off];
        __syncthreads();
    }
    if (tid == 0) bsums[blockIdx.x] = lds[0];
}

__global__ void scan_bsums_kernel(int* __restrict__ bsums, int nb, int* __restrict__ total_out) {
    if (threadIdx.x == 0 && blockIdx.x == 0) {
        int acc = 0;
        for (int b = 0; b < nb; ++b) {
            int v = bsums[b];
            bsums[b] = acc;
            acc += v;
        }
        *total_out = acc;
    }
}

__global__ void scan_final_kernel(const int* __restrict__ cnt, const int* __restrict__ bsums,
                                  int* __restrict__ rp) {
    __shared__ int lds[256];
    int tid = threadIdx.x;
    int base = blockIdx.x * 1024 + tid * 4;
    int v[4];
    int ts = 0;
#pragma unroll
    for (int i = 0; i < 4; ++i) {
        v[i] = (base + i < N_NODES) ? cnt[base + i] : 0;
        ts += v[i];
    }
    lds[tid] = ts;
    __syncthreads();
    for (int off = 1; off < 256; off <<= 1) {
        int t = (tid >= off) ? lds[tid - off] : 0;
        __syncthreads();
        lds[tid] += t;
        __syncthreads();
    }
    int run = lds[tid] - ts + bsums[blockIdx.x];
#pragma unroll
    for (int i = 0; i < 4; ++i) {
        if (base + i < N_NODES) rp[base + i] = run;
        run += v[i];
    }
}

__global__ void bucket_fill_kernel(const int* __restrict__ key, int* __restrict__ fill,
                                   int* __restrict__ raw) {
    int e = blockIdx.x * blockDim.x + threadIdx.x;
    if (e >= N_EDGES) return;
    int slot = atomicAdd(&fill[key[e]], 1);
    raw[slot] = e;
}

// per-row rank-selection sort by edge id: deterministic final layout
__global__ void sort_rows_kernel(const int* __restrict__ rp, const int* __restrict__ raw,
                                 int* __restrict__ sorted) {
    int n = blockIdx.x * blockDim.x + threadIdx.x;
    if (n >= N_NODES) return;
    int beg = rp[n], end = rp[n + 1];
    for (int i = beg; i < end; ++i) {
        int v = raw[i];
        int r = 0;
        for (int j = beg; j < end; ++j) r += (raw[j] < v);
        sorted[beg + r] = v;
    }
}

// dis[n] = 1/sqrtf(f32 sum of w over src-row n, ascending edge id), 0 if deg<=0
__global__ void deg_dis_kernel(const int* __restrict__ rp_src, const int* __restrict__ sorted,
                               const float* __restrict__ w, float* __restrict__ dis) {
#pragma clang fp contract(off)
    {
        int n = blockIdx.x * blockDim.x + threadIdx.x;
        if (n >= N_NODES) return;
        float d = 0.f;
        int beg = rp_src[n], end = rp_src[n + 1];
        for (int j = beg; j < end; ++j) d = d + w[sorted[j]];
        dis[n] = (d > 0.f) ? (1.0f / sqrtf(d)) : 0.f;
    }
}

// packed[j] = {src, ((-dis[s]) * w) * dis[d]}
__global__ void csr_fill_kernel(const int* __restrict__ sorted, const int* __restrict__ src,
                                const int* __restrict__ dst, const float* __restrict__ w,
                                const float* __restrict__ dis, int2* __restrict__ packed) {
#pragma clang fp contract(off)
    {
        int j = blockIdx.x * blockDim.x + threadIdx.x;
        if (j >= N_EDGES) return;
        int e = sorted[j];
        int s = src[e], d = dst[e];
        float cw = ((-dis[s]) * w[e]) * dis[d];
        packed[j] = make_int2(s, __float_as_int(cw));
    }
}

// ==================== per-layer kernels (f32, rounding-matched) ====================

// thread per (n,co): acc[n*SACC+co] = fmaf-chain over ci of hin[n*SIN+ci]*W0[ci,co]
template <int CIN, int COUT, int SIN, int SACC>
__global__ void layer_init_kernel(const float* __restrict__ hin, const float* __restrict__ W0,
                                  float* __restrict__ acc) {
    int t = blockIdx.x * blockDim.x + threadIdx.x;
    if (t >= N_NODES * COUT) return;
    int n = t / COUT, co = t - n * COUT;
    const float* hr = hin + (size_t)n * SIN;
    float m = 0.f;
#pragma unroll
    for (int ci = 0; ci < CIN; ++ci) m = fmaf(hr[ci], W0[ci * COUT + co], m);
    acc[(size_t)n * SACC + co] = m;
}

// Grouped-channel prop+matmul. Block = R rows x LANES lanes; lane owns GS
// consecutive channels (GS=4 -> one aligned float4 gather/edge; GS=2 -> float2).
// Per-channel gather chains in ascending edge-id order (mul rounded then add);
// recurrence; LDS handoff; ascending-ci fmaf matmul chain; acc += m.
// All chains bit-identical to r7. Edge loop manually unrolled x2 with plain
// loads: both edge records + both gathers issue before the (order-preserved)
// add chains -> 2x memory-level parallelism.
template <int CIN, int COUT, int SIN, int SACC, int GS, int LANES, int R>
__global__ __launch_bounds__(LANES* R) void prop_mm_kernel(
    const int* __restrict__ rp, const int2* __restrict__ pk, const float* __restrict__ hin,
    const float* __restrict__ prev, const float* __restrict__ Wk, int rec,
    float* __restrict__ tx_out, float* __restrict__ acc) {
#pragma clang fp contract(off)
    {
        __shared__ float tls[R][LANES * GS];
        int r = threadIdx.x / LANES;
        int lane = threadIdx.x - r * LANES;
        int n = blockIdx.x * R + r;
        bool vn = (n < N_NODES);
        if (vn) {
            int c0 = lane * GS;
            float s[GS];
#pragma unroll
            for (int g = 0; g < GS; ++g) s[g] = 0.f;
            int beg = rp[n], end = rp[n + 1];
            int j = beg;
            if constexpr (GS == 4) {
                for (; j + 1 < end; j += 2) {
                    int2 pa = pk[j];
                    int2 pb = pk[j + 1];
                    float wa = __int_as_float(pa.y);
                    float wb = __int_as_float(pb.y);
                    const float4 qa = *reinterpret_cast<const float4*>(hin + (size_t)pa.x * SIN + c0);
                    const float4 qb = *reinterpret_cast<const float4*>(hin + (size_t)pb.x * SIN + c0);
                    s[0] = s[0] + (wa * qa.x);
                    s[1] = s[1] + (wa * qa.y);
                    s[2] = s[2] + (wa * qa.z);
                    s[3] = s[3] + (wa * qa.w);
                    s[0] = s[0] + (wb * qb.x);
                    s[1] = s[1] + (wb * qb.y);
                    s[2] = s[2] + (wb * qb.z);
                    s[3] = s[3] + (wb * qb.w);
                }
                if (j < end) {
                    int2 p = pk[j];
                    float w = __int_as_float(p.y);
                    const float4 q = *reinterpret_cast<const float4*>(hin + (size_t)p.x * SIN + c0);
                    s[0] = s[0] + (w * q.x);
                    s[1] = s[1] + (w * q.y);
                    s[2] = s[2] + (w * q.z);
                    s[3] = s[3] + (w * q.w);
                }
            } else {  // GS == 2
                for (; j + 1 < end; j += 2) {
                    int2 pa = pk[j];
                    int2 pb = pk[j + 1];
                    float wa = __int_as_float(pa.y);
                    float wb = __int_as_float(pb.y);
                    const float2 qa = *reinterpret_cast<const float2*>(hin + (size_t)pa.x * SIN + c0);
                    const float2 qb = *reinterpret_cast<const float2*>(hin + (size_t)pb.x * SIN + c0);
                    s[0] = s[0] + (wa * qa.x);
                    s[1] = s[1] + (wa * qa.y);
                    s[0] = s[0] + (wb * qb.x);
                    s[1] = s[1] + (wb * qb.y);
                }
                if (j < end) {
                    int2 p = pk[j];
                    float w = __int_as_float(p.y);
                    const float2 q = *reinterpret_cast<const float2*>(hin + (size_t)p.x * SIN + c0);
                    s[0] = s[0] + (w * q.x);
                    s[1] = s[1] + (w * q.y);
                }
            }
            float t[GS];
            if (rec) {
#pragma unroll
                for (int g = 0; g < GS; ++g) t[g] = 2.f * s[g] - prev[(size_t)n * SIN + c0 + g];
            } else {
#pragma unroll
                for (int g = 0; g < GS; ++g) t[g] = s[g];
            }
#pragma unroll
            for (int g = 0; g < GS; ++g) tls[r][c0 + g] = t[g];
            if constexpr (GS == 4) {
                *reinterpret_cast<float4*>(tx_out + (size_t)n * SIN + c0) =
                    make_float4(t[0], t[1], t[2], t[3]);
            } else {
                *reinterpret_cast<float2*>(tx_out + (size_t)n * SIN + c0) =
                    make_float2(t[0], t[1]);
            }
        }
        __syncthreads();
        if (vn) {
            for (int co = lane; co < COUT; co += LANES) {
                float m = 0.f;
#pragma unroll
                for (int ci = 0; ci < CIN; ++ci) m = fmaf(tls[r][ci], Wk[ci * COUT + co], m);
                acc[(size_t)n * SACC + co] = acc[(size_t)n * SACC + co] + m;
            }
        }
    }
}

// a = silu(a + b) at padded stride S, real channels C only
template <int C, int S>
__global__ void silu_bias_kernel(float* __restrict__ a, const float* __restrict__ b) {
#pragma clang fp contract(off)
    {
        int t = blockIdx.x * blockDim.x + threadIdx.x;
        if (t >= N_NODES * C) return;
        int n = t / C, c = t - n * C;
        float x = a[(size_t)n * S + c] + b[c];
        float sig = 1.f / (1.f + expf(-x));
        a[(size_t)n * S + c] = x * sig;
    }
}

// out[n] = sigmoid(h[n,:27] @ W4), h at stride 28
__global__ void final_kernel(const float* __restrict__ h, const float* __restrict__ W4,
                             float* __restrict__ out) {
#pragma clang fp contract(off)
    {
        int n = blockIdx.x * blockDim.x + threadIdx.x;
        if (n >= N_NODES) return;
        const float* hr = h + (size_t)n * 28;
        float m = 0.f;
#pragma unroll
        for (int ci = 0; ci < 27; ++ci) m = fmaf(hr[ci], W4[ci], m);
        out[n] = 1.f / (1.f + expf(-m));
    }
}

__global__ void signal_kernel(float* __restrict__ out, float val) {
    int n = blockIdx.x * blockDim.x + threadIdx.x;
    if (n < N_NODES) out[n] = val;
}

// ==================== host driver ====================

static void run_scan(const int* cnt, int* bsums, int* rp, hipStream_t stream) {
    const int nb = (N_NODES + 1023) / 1024;  // 98
    scan_partial_kernel<<<nb, 256, 0, stream>>>(cnt, bsums);
    scan_bsums_kernel<<<1, 64, 0, stream>>>(bsums, nb, rp + N_NODES);
    scan_final_kernel<<<nb, 256, 0, stream>>>(cnt, bsums, rp);
}

template <int CIN, int COUT, int SIN, int SACC, int GS, int LANES, int R>
static void run_layer(int K, const float* hin, const float* W, float* acc, float* b0, float* b1,
                      float* b2, const int* rp, const int2* pk, hipStream_t stream) {
    const int gInit = (N_NODES * COUT + BS - 1) / BS;
    const int gProp = (N_NODES + R - 1) / R;
    layer_init_kernel<CIN, COUT, SIN, SACC><<<gInit, BS, 0, stream>>>(hin, W, acc);
    if (K > 1) {
        float* bufs[3] = {b0, b1, b2};
        prop_mm_kernel<CIN, COUT, SIN, SACC, GS, LANES, R><<<gProp, LANES * R, 0, stream>>>(
            rp, pk, hin, nullptr, W + 1 * CIN * COUT, 0, bufs[0], acc);
        const float* pm2 = hin;      // tx_{k-2}
        const float* pm1 = bufs[0];  // tx_{k-1}
        for (int k = 2; k < K; ++k) {
            float* outb = bufs[(k - 1) % 3];  // k=2->b1, k=3->b2, k=4->b0, ...
            prop_mm_kernel<CIN, COUT, SIN, SACC, GS, LANES, R><<<gProp, LANES * R, 0, stream>>>(
                rp, pk, pm1, pm2, W + k * CIN * COUT, 1, outb, acc);
            pm2 = pm1;
            pm1 = outb;
        }
    }
}

extern "C" void kernel_launch(void* const* d_in, const int* in_sizes, int n_in, void* d_out,
                              int out_size, void* d_ws, size_t ws_size, hipStream_t stream) {
    const float* x  = (const float*)d_in[0];
    const int* idx  = (const int*)d_in[1];
    const float* ew = (const float*)d_in[2];
    const float* W1 = (const float*)d_in[3];
    const float* b1 = (const float*)d_in[4];
    const float* W2 = (const float*)d_in[5];
    const float* b2 = (const float*)d_in[6];
    const float* W3 = (const float*)d_in[7];
    const float* b3 = (const float*)d_in[8];
    const float* W4 = (const float*)d_in[9];
    float* out = (float*)d_out;
    (void)in_sizes; (void)n_in; (void)out_size;

    const int* src = idx;
    const int* dst = idx + N_EDGES;

    // workspace carve-up (256B aligned) — r9's exact layout, ~76.8 MB
    size_t off = 0;
    auto alloc = [&](size_t bytes) {
        size_t o = off;
        off = (off + bytes + 255) & ~(size_t)255;
        return o;
    };
    char* ws = (char*)d_ws;
    int*   cnt     = (int*)(ws + alloc(N_NODES * 4));          // counts -> fill cursors
    int*   rp_src  = (int*)(ws + alloc((N_NODES + 1) * 4));
    int*   rp_dst  = (int*)(ws + alloc((N_NODES + 1) * 4));
    float* dis     = (float*)(ws + alloc(N_NODES * 4));
    int*   bsums   = (int*)(ws + alloc(512));
    int2*  packed  = (int2*)(ws + alloc((size_t)N_EDGES * 8));
    float* t0      = (float*)(ws + alloc((size_t)N_NODES * 20 * 4));  // tx, stride<=20
    float* t1      = (float*)(ws + alloc((size_t)N_NODES * 20 * 4));
    float* t2      = (float*)(ws + alloc((size_t)N_NODES * 20 * 4));
    float* accA    = (float*)(ws + alloc((size_t)N_NODES * 16 * 4));  // L1 out, stride 16
    float* accB    = (float*)(ws + alloc((size_t)N_NODES * 20 * 4));  // L2 out, stride 20
    float* accC    = (float*)(ws + alloc((size_t)N_NODES * 28 * 4));  // L3 out, stride 28
    const size_t NEED = off;
    // setup-only aliases (t/acc buffers are dead during setup):
    int* raw    = (int*)t0;  // 12.8MB, spans t0+part of t1 (contiguous allocs)
    int* sorted = (int*)t2;  // 12.8MB, spans t2+part of accA (contiguous allocs)

    int gE = (N_EDGES + BS - 1) / BS;
    int gN = (N_NODES + BS - 1) / BS;

    if (ws_size < NEED) {  // diagnostic: reveal ws_size as 6000+MB in absmax
        signal_kernel<<<gN, BS, 0, stream>>>(
            out, 6000.0f + (float)(ws_size / (1024.0 * 1024.0)));
        return;
    }

    // ---- src-keyed buckets -> deterministic deg -> dis ----
    (void)hipMemsetAsync(cnt, 0, N_NODES * 4, stream);
    count_kernel<<<gE, BS, 0, stream>>>(src, cnt);
    run_scan(cnt, bsums, rp_src, stream);
    (void)hipMemcpyAsync(cnt, rp_src, N_NODES * 4, hipMemcpyDeviceToDevice, stream);
    bucket_fill_kernel<<<gE, BS, 0, stream>>>(src, cnt, raw);
    sort_rows_kernel<<<gN, BS, 0, stream>>>(rp_src, raw, sorted);
    deg_dis_kernel<<<gN, BS, 0, stream>>>(rp_src, sorted, ew, dis);

    // ---- dst-keyed buckets -> deterministic packed CSR ----
    (void)hipMemsetAsync(cnt, 0, N_NODES * 4, stream);
    count_kernel<<<gE, BS, 0, stream>>>(dst, cnt);
    run_scan(cnt, bsums, rp_dst, stream);
    (void)hipMemcpyAsync(cnt, rp_dst, N_NODES * 4, hipMemcpyDeviceToDevice, stream);
    bucket_fill_kernel<<<gE, BS, 0, stream>>>(dst, cnt, raw);
    sort_rows_kernel<<<gN, BS, 0, stream>>>(rp_dst, raw, sorted);
    csr_fill_kernel<<<gE, BS, 0, stream>>>(sorted, src, dst, ew, dis, packed);

    // ---- layers ----
    // L1: CIN=2 (x, stride 2), out accA stride 16; 1 lane x 256 rows (float2 gather,
    //     single pk load per edge per node — no redundant lane loads)
    run_layer<2, 14, 2, 16, 2, 1, 256>(39, x, W1, accA, t0, t1, t2, rp_dst, packed, stream);
    silu_bias_kernel<14, 16><<<(N_NODES * 14 + BS - 1) / BS, BS, 0, stream>>>(accA, b1);
    // L2: CIN=14 @ stride 16 (64B rows), out accB stride 20; 4 lanes x 64 rows
    run_layer<14, 20, 16, 20, 4, 4, 64>(43, accA, W2, accB, t0, t1, t2, rp_dst, packed, stream);
    silu_bias_kernel<20, 20><<<(N_NODES * 20 + BS - 1) / BS, BS, 0, stream>>>(accB, b2);
    // L3: CIN=20 @ stride 20 (PACKED 8MB — footprint beats alignment), out accC stride 28; 5x51
    run_layer<20, 27, 20, 28, 4, 5, 51>(45, accB, W3, accC, t0, t1, t2, rp_dst, packed, stream);
    silu_bias_kernel<27, 28><<<(N_NODES * 27 + BS - 1) / BS, BS, 0, stream>>>(accC, b3);
    final_kernel<<<gN, BS, 0, stream>>>(accC, W4, out);
}

// Round 13
// 8961.132 us; speedup vs baseline: 1.5320x; 1.0646x over previous
//
#include <hip/hip_runtime.h>
#include <math.h>

#define N_NODES 100000
#define N_EDGES 3200000
#define BS 256

// ==================== setup: deterministic CSR construction ====================
// All-f32 data path, rounding-matched to the numpy reference (absmax 8.4e-11,
// rounds 7-12):
//  - bucket sums in ascending edge-id order (np.add.at semantics)
//  - products rounded separately from adds in the SpMV (np: norm*h then add.at)
//  - matmuls as ascending-k fmaf chains from 0, then one add
//  - dis = 1/sqrtf
// f64 is provably WRONG here (4 distinct f64 impls -> absmax 0.9999987).
// EVERY fp chain must stay bit-identical under refactors: parallelize only
// across independent chains (channels, rows), never within one.
//
// Perf model (r9/r11/r12 A/B): prop gathers are latency-bound (3.3 TB/s of
// 64B-sector touches vs ~35 TB/s L2 ceiling); gathered state must stay PACKED
// (stride 20 @ 8MB beats stride 32 @ 12.8MB by 35%); no nontemporal on pk.
// r12->r13: unroll-4 edge loop (4 gathers in flight), fused src+dst setup
// passes (one edge-stream read for both counts, one for both fills).

// one pass over edges: count both src and dst buckets
__global__ void count2_kernel(const int* __restrict__ src, const int* __restrict__ dst,
                              int* __restrict__ cnt_s, int* __restrict__ cnt_d) {
    int e = blockIdx.x * blockDim.x + threadIdx.x;
    if (e < N_EDGES) {
        atomicAdd(&cnt_s[src[e]], 1);
        atomicAdd(&cnt_d[dst[e]], 1);
    }
}

__global__ void scan_partial_kernel(const int* __restrict__ cnt, int* __restrict__ bsums) {
    __shared__ int lds[256];
    int tid = threadIdx.x;
    int base = blockIdx.x * 1024 + tid * 4;
    int s = 0;
#pragma unroll
    for (int i = 0; i < 4; ++i) s += (base + i < N_NODES) ? cnt[base + i] : 0;
    lds[tid] = s;
    __syncthreads();
    for (int off = 128; off > 0; off >>= 1) {
        if (tid < off) lds[tid] += lds[tid + off];
        __syncthreads();
    }
    if (tid == 0) bsums[blockIdx.x] = lds[0];
}

__global__ void scan_bsums_kernel(int* __restrict__ bsums, int nb, int* __restrict__ total_out) {
    if (threadIdx.x == 0 && blockIdx.x == 0) {
        int acc = 0;
        for (int b = 0; b < nb; ++b) {
            int v = bsums[b];
            bsums[b] = acc;
            acc += v;
        }
        *total_out = acc;
    }
}

__global__ void scan_final_kernel(const int* __restrict__ cnt, const int* __restrict__ bsums,
                                  int* __restrict__ rp) {
    __shared__ int lds[256];
    int tid = threadIdx.x;
    int base = blockIdx.x * 1024 + tid * 4;
    int v[4];
    int ts = 0;
#pragma unroll
    for (int i = 0; i < 4; ++i) {
        v[i] = (base + i < N_NODES) ? cnt[base + i] : 0;
        ts += v[i];
    }
    lds[tid] = ts;
    __syncthreads();
    for (int off = 1; off < 256; off <<= 1) {
        int t = (tid >= off) ? lds[tid - off] : 0;
        __syncthreads();
        lds[tid] += t;
        __syncthreads();
    }
    int run = lds[tid] - ts + bsums[blockIdx.x];
#pragma unroll
    for (int i = 0; i < 4; ++i) {
        if (base + i < N_NODES) rp[base + i] = run;
        run += v[i];
    }
}

// one pass over edges: scatter edge ids into both src- and dst-keyed buckets
__global__ void fill2_kernel(const int* __restrict__ src, const int* __restrict__ dst,
                             int* __restrict__ fill_s, int* __restrict__ fill_d,
                             int* __restrict__ raw_s, int* __restrict__ raw_d) {
    int e = blockIdx.x * blockDim.x + threadIdx.x;
    if (e >= N_EDGES) return;
    int slot_s = atomicAdd(&fill_s[src[e]], 1);
    raw_s[slot_s] = e;
    int slot_d = atomicAdd(&fill_d[dst[e]], 1);
    raw_d[slot_d] = e;
}

// per-row rank-selection sort by edge id: deterministic final layout
__global__ void sort_rows_kernel(const int* __restrict__ rp, const int* __restrict__ raw,
                                 int* __restrict__ sorted) {
    int n = blockIdx.x * blockDim.x + threadIdx.x;
    if (n >= N_NODES) return;
    int beg = rp[n], end = rp[n + 1];
    for (int i = beg; i < end; ++i) {
        int v = raw[i];
        int r = 0;
        for (int j = beg; j < end; ++j) r += (raw[j] < v);
        sorted[beg + r] = v;
    }
}

// dis[n] = 1/sqrtf(f32 sum of w over src-row n, ascending edge id), 0 if deg<=0
__global__ void deg_dis_kernel(const int* __restrict__ rp_src, const int* __restrict__ sorted,
                               const float* __restrict__ w, float* __restrict__ dis) {
#pragma clang fp contract(off)
    {
        int n = blockIdx.x * blockDim.x + threadIdx.x;
        if (n >= N_NODES) return;
        float d = 0.f;
        int beg = rp_src[n], end = rp_src[n + 1];
        for (int j = beg; j < end; ++j) d = d + w[sorted[j]];
        dis[n] = (d > 0.f) ? (1.0f / sqrtf(d)) : 0.f;
    }
}

// packed[j] = {src, ((-dis[s]) * w) * dis[d]}
__global__ void csr_fill_kernel(const int* __restrict__ sorted, const int* __restrict__ src,
                                const int* __restrict__ dst, const float* __restrict__ w,
                                const float* __restrict__ dis, int2* __restrict__ packed) {
#pragma clang fp contract(off)
    {
        int j = blockIdx.x * blockDim.x + threadIdx.x;
        if (j >= N_EDGES) return;
        int e = sorted[j];
        int s = src[e], d = dst[e];
        float cw = ((-dis[s]) * w[e]) * dis[d];
        packed[j] = make_int2(s, __float_as_int(cw));
    }
}

// ==================== per-layer kernels (f32, rounding-matched) ====================

// thread per (n,co): acc[n*SACC+co] = fmaf-chain over ci of hin[n*SIN+ci]*W0[ci,co]
template <int CIN, int COUT, int SIN, int SACC>
__global__ void layer_init_kernel(const float* __restrict__ hin, const float* __restrict__ W0,
                                  float* __restrict__ acc) {
    int t = blockIdx.x * blockDim.x + threadIdx.x;
    if (t >= N_NODES * COUT) return;
    int n = t / COUT, co = t - n * COUT;
    const float* hr = hin + (size_t)n * SIN;
    float m = 0.f;
#pragma unroll
    for (int ci = 0; ci < CIN; ++ci) m = fmaf(hr[ci], W0[ci * COUT + co], m);
    acc[(size_t)n * SACC + co] = m;
}

// Grouped-channel prop+matmul. Block = R rows x LANES lanes; lane owns GS
// consecutive channels (GS=4 -> one aligned float4 gather/edge; GS=2 -> float2).
// Per-channel gather chains in ascending edge-id order (mul rounded then add);
// recurrence; LDS handoff; ascending-ci fmaf matmul chain; acc += m.
// Edge loop unrolled x4 with plain loads: 4 edge records + 4 gathers issue
// before the (order-preserved) add chains -> 4x memory-level parallelism.
// Per-channel add order is strictly ascending edge id -> bit-exact vs r7.
template <int CIN, int COUT, int SIN, int SACC, int GS, int LANES, int R>
__global__ __launch_bounds__(LANES* R) void prop_mm_kernel(
    const int* __restrict__ rp, const int2* __restrict__ pk, const float* __restrict__ hin,
    const float* __restrict__ prev, const float* __restrict__ Wk, int rec,
    float* __restrict__ tx_out, float* __restrict__ acc) {
#pragma clang fp contract(off)
    {
        __shared__ float tls[R][LANES * GS];
        int r = threadIdx.x / LANES;
        int lane = threadIdx.x - r * LANES;
        int n = blockIdx.x * R + r;
        bool vn = (n < N_NODES);
        if (vn) {
            int c0 = lane * GS;
            float s[GS];
#pragma unroll
            for (int g = 0; g < GS; ++g) s[g] = 0.f;
            int beg = rp[n], end = rp[n + 1];
            int j = beg;
            if constexpr (GS == 4) {
                for (; j + 3 < end; j += 4) {
                    int2 p0 = pk[j];
                    int2 p1 = pk[j + 1];
                    int2 p2 = pk[j + 2];
                    int2 p3 = pk[j + 3];
                    const float4 q0 = *reinterpret_cast<const float4*>(hin + (size_t)p0.x * SIN + c0);
                    const float4 q1 = *reinterpret_cast<const float4*>(hin + (size_t)p1.x * SIN + c0);
                    const float4 q2 = *reinterpret_cast<const float4*>(hin + (size_t)p2.x * SIN + c0);
                    const float4 q3 = *reinterpret_cast<const float4*>(hin + (size_t)p3.x * SIN + c0);
                    float w0 = __int_as_float(p0.y), w1 = __int_as_float(p1.y);
                    float w2 = __int_as_float(p2.y), w3 = __int_as_float(p3.y);
                    s[0] = s[0] + (w0 * q0.x); s[1] = s[1] + (w0 * q0.y);
                    s[2] = s[2] + (w0 * q0.z); s[3] = s[3] + (w0 * q0.w);
                    s[0] = s[0] + (w1 * q1.x); s[1] = s[1] + (w1 * q1.y);
                    s[2] = s[2] + (w1 * q1.z); s[3] = s[3] + (w1 * q1.w);
                    s[0] = s[0] + (w2 * q2.x); s[1] = s[1] + (w2 * q2.y);
                    s[2] = s[2] + (w2 * q2.z); s[3] = s[3] + (w2 * q2.w);
                    s[0] = s[0] + (w3 * q3.x); s[1] = s[1] + (w3 * q3.y);
                    s[2] = s[2] + (w3 * q3.z); s[3] = s[3] + (w3 * q3.w);
                }
                for (; j < end; ++j) {
                    int2 p = pk[j];
                    float w = __int_as_float(p.y);
                    const float4 q = *reinterpret_cast<const float4*>(hin + (size_t)p.x * SIN + c0);
                    s[0] = s[0] + (w * q.x); s[1] = s[1] + (w * q.y);
                    s[2] = s[2] + (w * q.z); s[3] = s[3] + (w * q.w);
                }
            } else {  // GS == 2
                for (; j + 3 < end; j += 4) {
                    int2 p0 = pk[j];
                    int2 p1 = pk[j + 1];
                    int2 p2 = pk[j + 2];
                    int2 p3 = pk[j + 3];
                    const float2 q0 = *reinterpret_cast<const float2*>(hin + (size_t)p0.x * SIN + c0);
                    const float2 q1 = *reinterpret_cast<const float2*>(hin + (size_t)p1.x * SIN + c0);
                    const float2 q2 = *reinterpret_cast<const float2*>(hin + (size_t)p2.x * SIN + c0);
                    const float2 q3 = *reinterpret_cast<const float2*>(hin + (size_t)p3.x * SIN + c0);
                    float w0 = __int_as_float(p0.y), w1 = __int_as_float(p1.y);
                    float w2 = __int_as_float(p2.y), w3 = __int_as_float(p3.y);
                    s[0] = s[0] + (w0 * q0.x); s[1] = s[1] + (w0 * q0.y);
                    s[0] = s[0] + (w1 * q1.x); s[1] = s[1] + (w1 * q1.y);
                    s[0] = s[0] + (w2 * q2.x); s[1] = s[1] + (w2 * q2.y);
                    s[0] = s[0] + (w3 * q3.x); s[1] = s[1] + (w3 * q3.y);
                }
                for (; j < end; ++j) {
                    int2 p = pk[j];
                    float w = __int_as_float(p.y);
                    const float2 q = *reinterpret_cast<const float2*>(hin + (size_t)p.x * SIN + c0);
                    s[0] = s[0] + (w * q.x); s[1] = s[1] + (w * q.y);
                }
            }
            float t[GS];
            if (rec) {
#pragma unroll
                for (int g = 0; g < GS; ++g) t[g] = 2.f * s[g] - prev[(size_t)n * SIN + c0 + g];
            } else {
#pragma unroll
                for (int g = 0; g < GS; ++g) t[g] = s[g];
            }
#pragma unroll
            for (int g = 0; g < GS; ++g) tls[r][c0 + g] = t[g];
            if constexpr (GS == 4) {
                *reinterpret_cast<float4*>(tx_out + (size_t)n * SIN + c0) =
                    make_float4(t[0], t[1], t[2], t[3]);
            } else {
                *reinterpret_cast<float2*>(tx_out + (size_t)n * SIN + c0) =
                    make_float2(t[0], t[1]);
            }
        }
        __syncthreads();
        if (vn) {
            for (int co = lane; co < COUT; co += LANES) {
                float m = 0.f;
#pragma unroll
                for (int ci = 0; ci < CIN; ++ci) m = fmaf(tls[r][ci], Wk[ci * COUT + co], m);
                acc[(size_t)n * SACC + co] = acc[(size_t)n * SACC + co] + m;
            }
        }
    }
}

// a = silu(a + b) at padded stride S, real channels C only
template <int C, int S>
__global__ void silu_bias_kernel(float* __restrict__ a, const float* __restrict__ b) {
#pragma clang fp contract(off)
    {
        int t = blockIdx.x * blockDim.x + threadIdx.x;
        if (t >= N_NODES * C) return;
        int n = t / C, c = t - n * C;
        float x = a[(size_t)n * S + c] + b[c];
        float sig = 1.f / (1.f + expf(-x));
        a[(size_t)n * S + c] = x * sig;
    }
}

// out[n] = sigmoid(h[n,:27] @ W4), h at stride 28
__global__ void final_kernel(const float* __restrict__ h, const float* __restrict__ W4,
                             float* __restrict__ out) {
#pragma clang fp contract(off)
    {
        int n = blockIdx.x * blockDim.x + threadIdx.x;
        if (n >= N_NODES) return;
        const float* hr = h + (size_t)n * 28;
        float m = 0.f;
#pragma unroll
        for (int ci = 0; ci < 27; ++ci) m = fmaf(hr[ci], W4[ci], m);
        out[n] = 1.f / (1.f + expf(-m));
    }
}

__global__ void signal_kernel(float* __restrict__ out, float val) {
    int n = blockIdx.x * blockDim.x + threadIdx.x;
    if (n < N_NODES) out[n] = val;
}

// ==================== host driver ====================

static void run_scan(const int* cnt, int* bsums, int* rp, hipStream_t stream) {
    const int nb = (N_NODES + 1023) / 1024;  // 98
    scan_partial_kernel<<<nb, 256, 0, stream>>>(cnt, bsums);
    scan_bsums_kernel<<<1, 64, 0, stream>>>(bsums, nb, rp + N_NODES);
    scan_final_kernel<<<nb, 256, 0, stream>>>(cnt, bsums, rp);
}

template <int CIN, int COUT, int SIN, int SACC, int GS, int LANES, int R>
static void run_layer(int K, const float* hin, const float* W, float* acc, float* b0, float* b1,
                      float* b2, const int* rp, const int2* pk, hipStream_t stream) {
    const int gInit = (N_NODES * COUT + BS - 1) / BS;
    const int gProp = (N_NODES + R - 1) / R;
    layer_init_kernel<CIN, COUT, SIN, SACC><<<gInit, BS, 0, stream>>>(hin, W, acc);
    if (K > 1) {
        float* bufs[3] = {b0, b1, b2};
        prop_mm_kernel<CIN, COUT, SIN, SACC, GS, LANES, R><<<gProp, LANES * R, 0, stream>>>(
            rp, pk, hin, nullptr, W + 1 * CIN * COUT, 0, bufs[0], acc);
        const float* pm2 = hin;      // tx_{k-2}
        const float* pm1 = bufs[0];  // tx_{k-1}
        for (int k = 2; k < K; ++k) {
            float* outb = bufs[(k - 1) % 3];  // k=2->b1, k=3->b2, k=4->b0, ...
            prop_mm_kernel<CIN, COUT, SIN, SACC, GS, LANES, R><<<gProp, LANES * R, 0, stream>>>(
                rp, pk, pm1, pm2, W + k * CIN * COUT, 1, outb, acc);
            pm2 = pm1;
            pm1 = outb;
        }
    }
}

extern "C" void kernel_launch(void* const* d_in, const int* in_sizes, int n_in, void* d_out,
                              int out_size, void* d_ws, size_t ws_size, hipStream_t stream) {
    const float* x  = (const float*)d_in[0];
    const int* idx  = (const int*)d_in[1];
    const float* ew = (const float*)d_in[2];
    const float* W1 = (const float*)d_in[3];
    const float* b1 = (const float*)d_in[4];
    const float* W2 = (const float*)d_in[5];
    const float* b2 = (const float*)d_in[6];
    const float* W3 = (const float*)d_in[7];
    const float* b3 = (const float*)d_in[8];
    const float* W4 = (const float*)d_in[9];
    float* out = (float*)d_out;
    (void)in_sizes; (void)n_in; (void)out_size;

    const int* src = idx;
    const int* dst = idx + N_EDGES;

    // workspace carve-up (256B aligned) — ~77.2 MB
    size_t off = 0;
    auto alloc = [&](size_t bytes) {
        size_t o = off;
        off = (off + bytes + 255) & ~(size_t)255;
        return o;
    };
    char* ws = (char*)d_ws;
    int*   cnt_s   = (int*)(ws + alloc(N_NODES * 4));          // src counts -> fill cursors
    int*   cnt_d   = (int*)(ws + alloc(N_NODES * 4));          // dst counts -> fill cursors
    int*   rp_src  = (int*)(ws + alloc((N_NODES + 1) * 4));
    int*   rp_dst  = (int*)(ws + alloc((N_NODES + 1) * 4));
    float* dis     = (float*)(ws + alloc(N_NODES * 4));
    int*   bsums   = (int*)(ws + alloc(512));
    int2*  packed  = (int2*)(ws + alloc((size_t)N_EDGES * 8));
    // layer-phase pool (49.6 MB, contiguous). Setup aliases carved from its base:
    const size_t pool_off = alloc(0);
    float* t0      = (float*)(ws + alloc((size_t)N_NODES * 20 * 4));  // tx, stride<=20
    float* t1      = (float*)(ws + alloc((size_t)N_NODES * 20 * 4));
    float* t2      = (float*)(ws + alloc((size_t)N_NODES * 20 * 4));
    float* accA    = (float*)(ws + alloc((size_t)N_NODES * 16 * 4));  // L1 out, stride 16
    float* accB    = (float*)(ws + alloc((size_t)N_NODES * 20 * 4));  // L2 out, stride 20
    float* accC    = (float*)(ws + alloc((size_t)N_NODES * 28 * 4));  // L3 out, stride 28
    const size_t NEED = off;
    // setup-only aliases inside the pool (pool is 49.6MB; each array is 12.8MB):
    // raw_s @ +0, raw_d @ +16MB, sorted_s @ +32MB; sorted_d reuses +0 after
    // raw_s's last read (sort_s). All disjoint; pool first written by layers.
    char* pool = ws + pool_off;
    int* raw_s    = (int*)(pool);
    int* raw_d    = (int*)(pool + ((size_t)16 << 20));
    int* sorted_s = (int*)(pool + ((size_t)32 << 20));
    int* sorted_d = (int*)(pool);

    int gE = (N_EDGES + BS - 1) / BS;
    int gN = (N_NODES + BS - 1) / BS;

    if (ws_size < NEED) {  // diagnostic: reveal ws_size as 6000+MB in absmax
        signal_kernel<<<gN, BS, 0, stream>>>(
            out, 6000.0f + (float)(ws_size / (1024.0 * 1024.0)));
        return;
    }

    // ---- fused setup: one edge pass for both counts, one for both fills ----
    (void)hipMemsetAsync(cnt_s, 0, N_NODES * 4, stream);
    (void)hipMemsetAsync(cnt_d, 0, N_NODES * 4, stream);
    count2_kernel<<<gE, BS, 0, stream>>>(src, dst, cnt_s, cnt_d);
    run_scan(cnt_s, bsums, rp_src, stream);
    run_scan(cnt_d, bsums, rp_dst, stream);
    (void)hipMemcpyAsync(cnt_s, rp_src, N_NODES * 4, hipMemcpyDeviceToDevice, stream);
    (void)hipMemcpyAsync(cnt_d, rp_dst, N_NODES * 4, hipMemcpyDeviceToDevice, stream);
    fill2_kernel<<<gE, BS, 0, stream>>>(src, dst, cnt_s, cnt_d, raw_s, raw_d);
    sort_rows_kernel<<<gN, BS, 0, stream>>>(rp_src, raw_s, sorted_s);
    deg_dis_kernel<<<gN, BS, 0, stream>>>(rp_src, sorted_s, ew, dis);
    sort_rows_kernel<<<gN, BS, 0, stream>>>(rp_dst, raw_d, sorted_d);
    csr_fill_kernel<<<gE, BS, 0, stream>>>(sorted_d, src, dst, ew, dis, packed);

    // ---- layers ----
    // L1: CIN=2 (x, stride 2), out accA stride 16; 1 lane x 256 rows (float2 gather)
    run_layer<2, 14, 2, 16, 2, 1, 256>(39, x, W1, accA, t0, t1, t2, rp_dst, packed, stream);
    silu_bias_kernel<14, 16><<<(N_NODES * 14 + BS - 1) / BS, BS, 0, stream>>>(accA, b1);
    // L2: CIN=14 @ stride 16 (64B rows), out accB stride 20; 4 lanes x 64 rows
    run_layer<14, 20, 16, 20, 4, 4, 64>(43, accA, W2, accB, t0, t1, t2, rp_dst, packed, stream);
    silu_bias_kernel<20, 20><<<(N_NODES * 20 + BS - 1) / BS, BS, 0, stream>>>(accB, b2);
    // L3: CIN=20 @ stride 20 (PACKED 8MB), out accC stride 28; 5 lanes x 51 rows
    run_layer<20, 27, 20, 28, 4, 5, 51>(45, accB, W3, accC, t0, t1, t2, rp_dst, packed, stream);
    silu_bias_kernel<27, 28><<<(N_NODES * 27 + BS - 1) / BS, BS, 0, stream>>>(accC, b3);
    final_kernel<<<gN, BS, 0, stream>>>(accC, W4, out);
}